// Round 5
// baseline (164.849 us; speedup 1.0000x reference)
//
#include <hip/hip_runtime.h>
#include <hip/hip_bf16.h>

typedef __bf16 bf16x8 __attribute__((ext_vector_type(8)));
typedef float f32x4 __attribute__((ext_vector_type(4)));

#define N_NODES 50000
#define NEDGE 160000
#define CS 50176            // 49 * 1024, padded stride for per-rel count/indptr arrays
#define BLKS_PER_REL 49
#define HSZ ((size_t)N_NODES * 128)   // elements per node-feature buffer

// ---- workspace layout (bytes) ----
constexpr size_t OFF_WFRAG = 0;                                   // 131072
constexpr size_t OFF_XB    = 131072;                              // 2 * 12.8 MB bf16 x
constexpr size_t OFF_CNT   = OFF_XB + 2 * 12800000;               // 4*CS*4
constexpr size_t OFF_IPTR  = OFF_CNT + (size_t)4 * CS * 4;
constexpr size_t OFF_CUR   = OFF_IPTR + (size_t)4 * CS * 4;
constexpr size_t OFF_PART  = OFF_CUR + (size_t)4 * CS * 4;        // 196*4
constexpr size_t OFF_SRC   = OFF_PART + 1024;                     // 4*E*4

// Compose W[r] = w_comp[r,0]*weight[0] + w_comp[r,1]*weight[1], store bf16 in
// MFMA fragment order: offset = (((r*8+n)*4+kk)*64+lane)*8 + j
// element = W[r][k][o], k = kk*32 + (lane>>4)*8 + j, o = n*16 + (lane&15)
// (reads as B-operand = W, or as A-operand = W^T — we use the latter)
__global__ __launch_bounds__(256) void wfrag_kernel(const float* __restrict__ weight,
                                                    const float* __restrict__ wcomp,
                                                    __bf16* __restrict__ wfrag) {
    int tid = blockIdx.x * 256 + threadIdx.x;  // 65536 total
    int j    = tid & 7;
    int lane = (tid >> 3) & 63;
    int kk   = (tid >> 9) & 3;
    int n    = (tid >> 11) & 7;
    int r    = tid >> 14;
    int k = kk * 32 + ((lane >> 4) << 3) + j;
    int o = (n << 4) + (lane & 15);
    float v = wcomp[r * 2] * weight[k * 128 + o] +
              wcomp[r * 2 + 1] * weight[16384 + k * 128 + o];
    wfrag[tid] = (__bf16)v;
}

// xb[type] = bf16(x_type), vectorized: 8 floats -> uint4 of 8 bf16 per thread
__global__ __launch_bounds__(256) void cast_kernel(const float* __restrict__ x0,
                                                   const float* __restrict__ x1,
                                                   __bf16* __restrict__ xb) {
    int ty = blockIdx.y;
    const float* x = ty ? x1 : x0;
    __bf16* o = xb + (size_t)ty * HSZ;
    int i = blockIdx.x * 256 + threadIdx.x;      // float8 index, 800000 per type
    float4 f0 = reinterpret_cast<const float4*>(x)[2 * i];
    float4 f1 = reinterpret_cast<const float4*>(x)[2 * i + 1];
    union { __bf16 b[8]; uint4 v; } pk;
    pk.b[0] = (__bf16)f0.x; pk.b[1] = (__bf16)f0.y;
    pk.b[2] = (__bf16)f0.z; pk.b[3] = (__bf16)f0.w;
    pk.b[4] = (__bf16)f1.x; pk.b[5] = (__bf16)f1.y;
    pk.b[6] = (__bf16)f1.z; pk.b[7] = (__bf16)f1.w;
    reinterpret_cast<uint4*>(o)[i] = pk.v;
}

// counts[rel][d] += 1 for all 4 relations (counts pre-zeroed). i in [0, 4E).
__global__ __launch_bounds__(256) void hist4_kernel(const int* __restrict__ d0,
                                                    const int* __restrict__ d1,
                                                    const int* __restrict__ d2,
                                                    const int* __restrict__ d3,
                                                    int* __restrict__ counts) {
    int i = blockIdx.x * 256 + threadIdx.x;
    int rel = i / NEDGE;
    int e = i - rel * NEDGE;
    const int* dp = rel == 0 ? d0 : rel == 1 ? d1 : rel == 2 ? d2 : d3;
    atomicAdd(&counts[rel * CS + dp[e]], 1);
}

// Per-block partial sums: 49 blocks/rel, 1024 counts/block (int4 per thread).
__global__ __launch_bounds__(256) void block_sums_kernel(const int* __restrict__ counts,
                                                         int* __restrict__ partials) {
    int rel = blockIdx.x / BLKS_PER_REL;
    int blk = blockIdx.x - rel * BLKS_PER_REL;
    const int4* base = reinterpret_cast<const int4*>(counts + rel * CS) + blk * 256;
    int4 v = base[threadIdx.x];
    int s = v.x + v.y + v.z + v.w;
#pragma unroll
    for (int d = 1; d < 64; d <<= 1) s += __shfl_xor(s, d, 64);
    __shared__ int wsum[4];
    int wave = threadIdx.x >> 6;
    int lane = threadIdx.x & 63;
    if (lane == 0) wsum[wave] = s;
    __syncthreads();
    if (threadIdx.x == 0)
        partials[blockIdx.x] = wsum[0] + wsum[1] + wsum[2] + wsum[3];
}

// Exclusive scan + write indptr and cursor (int4 stores).
__global__ __launch_bounds__(256) void scan_write_kernel(const int* __restrict__ counts,
                                                         const int* __restrict__ partials,
                                                         int* __restrict__ indptr,
                                                         int* __restrict__ cursor) {
    int rel = blockIdx.x / BLKS_PER_REL;
    int blk = blockIdx.x - rel * BLKS_PER_REL;
    int lane = threadIdx.x & 63;
    int wave = threadIdx.x >> 6;

    int pv = (lane < blk) ? partials[rel * BLKS_PER_REL + lane] : 0;
#pragma unroll
    for (int d = 1; d < 64; d <<= 1) pv += __shfl_xor(pv, d, 64);

    const int4* base = reinterpret_cast<const int4*>(counts + rel * CS) + blk * 256;
    int4 v = base[threadIdx.x];
    int ts = v.x + v.y + v.z + v.w;

    int s = ts;
#pragma unroll
    for (int d = 1; d < 64; d <<= 1) {
        int n = __shfl_up(s, d, 64);
        if (lane >= d) s += n;
    }
    int exclw = s - ts;

    __shared__ int wtot[4];
    if (lane == 63) wtot[wave] = s;
    __syncthreads();
    int woff = 0;
    if (wave > 0) woff += wtot[0];
    if (wave > 1) woff += wtot[1];
    if (wave > 2) woff += wtot[2];

    int e0 = pv + woff + exclw;
    int4 ip;
    ip.x = e0;
    ip.y = e0 + v.x;
    ip.z = ip.y + v.y;
    ip.w = ip.z + v.z;
    reinterpret_cast<int4*>(indptr + rel * CS)[blk * 256 + threadIdx.x] = ip;
    reinterpret_cast<int4*>(cursor + rel * CS)[blk * 256 + threadIdx.x] = ip;
}

// srcids[rel][pos] = src with pos = cursor[rel][dst]++, all 4 relations
__global__ __launch_bounds__(256) void fill4_kernel(const int* __restrict__ s0, const int* __restrict__ d0,
                                                    const int* __restrict__ s1, const int* __restrict__ d1,
                                                    const int* __restrict__ s2, const int* __restrict__ d2,
                                                    const int* __restrict__ s3, const int* __restrict__ d3,
                                                    int* __restrict__ cursor,
                                                    int* __restrict__ srcids) {
    int i = blockIdx.x * 256 + threadIdx.x;
    int rel = i / NEDGE;
    int e = i - rel * NEDGE;
    const int* dp = rel == 0 ? d0 : rel == 1 ? d1 : rel == 2 ? d2 : d3;
    const int* sp = rel == 0 ? s0 : rel == 1 ? s1 : rel == 2 ? s2 : s3;
    int d = dp[e];
    int s = sp[e];
    int pos = atomicAdd(&cursor[rel * CS + d], 1);
    srcids[rel * NEDGE + pos] = s;
}

// Fused gather + MFMA: per block (4 waves) 64 dst nodes of type p = blockIdx.y.
// Phase 1: each wave gather-sums xb rows for its 16 nodes x 2 relations into
// wave-private LDS tiles (bf16). Phase 2: out = At0 @ W_p + At1 @ W_{p+2} + bias
// via operand-swapped MFMA (W^T as A) -> each lane stores 8x float4 contiguous.
__global__ __launch_bounds__(256) void gather_mm_kernel(const __bf16* __restrict__ xb,
                                                        const int* __restrict__ indptr,
                                                        const int* __restrict__ srcids,
                                                        const __bf16* __restrict__ wfrag,
                                                        const float* __restrict__ bias,
                                                        float* __restrict__ out) {
    __shared__ __bf16 At[2][64][136];   // pad 136: rows 272B (16B-aligned, bank-spread)
    const int p = blockIdx.y;
    const int base = blockIdx.x * 64;
    const int lane = threadIdx.x & 63;
    const int wave = threadIdx.x >> 6;
    const int g = lane >> 4;
    const int m15 = lane & 15;
    const int off = base + wave * 16;

    // preload the 17 indptr values per relation; distribute via shfl
    int idx = lane < 17 ? lane : 16;
    int ipA = indptr[(p + 0) * CS + off + idx];      // rel p   (src type 0)
    int ipB = indptr[(p + 2) * CS + off + idx];      // rel p+2 (src type 1)

    const unsigned int* xbu = reinterpret_cast<const unsigned int*>(xb);

    for (int t = 0; t < 16; ++t) {
#pragma unroll
        for (int q = 0; q < 2; ++q) {
            int beg = __shfl(q ? ipB : ipA, t, 64);
            int end = __shfl(q ? ipB : ipA, t + 1, 64);
            int d = end - beg;
            const int* sp = srcids + (size_t)(p + 2 * q) * NEDGE + beg;
            const unsigned int* xB = xbu + (size_t)q * (HSZ / 2);
            float a0 = 0.f, a1 = 0.f;
            for (int i = 0; i < d; i += 4) {
                unsigned int hv[4];
#pragma unroll
                for (int k2 = 0; k2 < 4; ++k2) {
                    int j = i + k2;
                    int jc = j < d ? j : d - 1;
                    int s = sp[jc];
                    unsigned int v = xB[(size_t)s * 64 + lane];
                    hv[k2] = j < d ? v : 0u;
                }
#pragma unroll
                for (int k2 = 0; k2 < 4; ++k2) {
                    union { unsigned int u; float f; } lo, hi;
                    lo.u = hv[k2] << 16;
                    hi.u = hv[k2] & 0xFFFF0000u;
                    a0 += lo.f;
                    a1 += hi.f;
                }
            }
            union { __bf16 b[2]; unsigned int u; } pk;
            pk.b[0] = (__bf16)a0;
            pk.b[1] = (__bf16)a1;
            reinterpret_cast<unsigned int*>(&At[q][wave * 16 + t][0])[lane] = pk.u;
        }
    }
    // tiles are wave-private: same-wave LDS RAW handled by lgkmcnt, no barrier.

    bf16x8 bfrag[2][4];
#pragma unroll
    for (int q = 0; q < 2; ++q)
#pragma unroll
        for (int kk = 0; kk < 4; ++kk)
            bfrag[q][kk] = *reinterpret_cast<const bf16x8*>(
                &At[q][wave * 16 + m15][kk * 32 + g * 8]);

    int node = off + m15;
    bool valid = node < N_NODES;
    float* orow = out + ((size_t)p * N_NODES + node) * 128;

#pragma unroll
    for (int n = 0; n < 8; ++n) {
        float4 bv = *reinterpret_cast<const float4*>(bias + n * 16 + g * 4);
        f32x4 acc = (f32x4){bv.x, bv.y, bv.z, bv.w};
#pragma unroll
        for (int q = 0; q < 2; ++q) {
            const bf16x8* wv = reinterpret_cast<const bf16x8*>(wfrag + (p + 2 * q) * 16384);
#pragma unroll
            for (int kk = 0; kk < 4; ++kk)
                acc = __builtin_amdgcn_mfma_f32_16x16x32_bf16(
                    wv[(n * 4 + kk) * 64 + lane], bfrag[q][kk], acc, 0, 0, 0);
        }
        if (valid)
            *reinterpret_cast<float4*>(orow + n * 16 + g * 4) =
                (float4){acc[0], acc[1], acc[2], acc[3]};
    }
}

extern "C" void kernel_launch(void* const* d_in, const int* in_sizes, int n_in,
                              void* d_out, int out_size, void* d_ws, size_t ws_size,
                              hipStream_t stream) {
    const float* x0     = (const float*)d_in[0];
    const float* x1     = (const float*)d_in[1];
    const float* weight = (const float*)d_in[2];
    const float* wcomp  = (const float*)d_in[3];
    const float* bias   = (const float*)d_in[4];
    const int* src[4] = {(const int*)d_in[5], (const int*)d_in[7],
                         (const int*)d_in[9], (const int*)d_in[11]};
    const int* dst[4] = {(const int*)d_in[6], (const int*)d_in[8],
                         (const int*)d_in[10], (const int*)d_in[12]};
    float* out = (float*)d_out;

    char* ws = (char*)d_ws;
    __bf16* wfrag = (__bf16*)(ws + OFF_WFRAG);
    __bf16* xb    = (__bf16*)(ws + OFF_XB);
    int* counts   = (int*)(ws + OFF_CNT);
    int* indptr   = (int*)(ws + OFF_IPTR);
    int* cursor   = (int*)(ws + OFF_CUR);
    int* partials = (int*)(ws + OFF_PART);
    int* srcids   = (int*)(ws + OFF_SRC);

    wfrag_kernel<<<256, 256, 0, stream>>>(weight, wcomp, wfrag);
    cast_kernel<<<dim3(3125, 2), 256, 0, stream>>>(x0, x1, xb);

    // ---- CSR build for all 4 relations ----
    hipMemsetAsync(counts, 0, (size_t)4 * CS * 4, stream);
    hist4_kernel<<<4 * NEDGE / 256, 256, 0, stream>>>(
        dst[0], dst[1], dst[2], dst[3], counts);
    block_sums_kernel<<<4 * BLKS_PER_REL, 256, 0, stream>>>(counts, partials);
    scan_write_kernel<<<4 * BLKS_PER_REL, 256, 0, stream>>>(counts, partials, indptr, cursor);
    fill4_kernel<<<4 * NEDGE / 256, 256, 0, stream>>>(
        src[0], dst[0], src[1], dst[1], src[2], dst[2], src[3], dst[3],
        cursor, srcids);

    // ---- fused gather-sum (x-space) + MFMA transform + bias ----
    gather_mm_kernel<<<dim3((N_NODES + 63) / 64, 2), 256, 0, stream>>>(
        xb, indptr, srcids, wfrag, bias, out);
}

// Round 6
// 148.651 us; speedup vs baseline: 1.1090x; 1.1090x over previous
//
#include <hip/hip_runtime.h>
#include <hip/hip_bf16.h>

typedef __bf16 bf16x8 __attribute__((ext_vector_type(8)));
typedef float f32x4 __attribute__((ext_vector_type(4)));

#define N_NODES 50000
#define NEDGE 160000
#define NSLOT (2 * N_NODES)          // 100000 dst slots (both ntypes)
#define CS2 100352                   // 98 * 1024, padded slot count for scan
#define BLKS 98
#define HSZ ((size_t)N_NODES * 128)

// ---- workspace layout (bytes) ----
constexpr size_t OFF_WFRAG = 0;                                    // 2 basis frag sets, 65536 B
constexpr size_t OFF_XB    = 65536;                                // 100k x 128 bf16 = 25.6 MB
constexpr size_t OFF_Y     = OFF_XB + 25600000;                    // 100k x 256 bf16 = 51.2 MB
constexpr size_t OFF_CNT   = OFF_Y + 51200000;                     // CS2*4
constexpr size_t OFF_IPTR  = OFF_CNT + (size_t)CS2 * 4;
constexpr size_t OFF_CUR   = OFF_IPTR + (size_t)CS2 * 4;
constexpr size_t OFF_PART  = OFF_CUR + (size_t)CS2 * 4;            // 98*4, pad 1024
constexpr size_t OFF_SRC   = OFF_PART + 1024;                      // 4E*4 = 2.56 MB

// Basis fragments: offset = (((b*8+n)*4+kk)*64+lane)*8 + j
// element = weight[b][k][o], k = kk*32 + (lane>>4)*8 + j, o = n*16 + (lane&15)
__global__ __launch_bounds__(256) void wfrag_kernel(const float* __restrict__ weight,
                                                    __bf16* __restrict__ wfrag) {
    int tid = blockIdx.x * 256 + threadIdx.x;  // 32768 total
    int j    = tid & 7;
    int lane = (tid >> 3) & 63;
    int kk   = (tid >> 9) & 3;
    int n    = (tid >> 11) & 7;
    int b    = tid >> 14;
    int k = kk * 32 + ((lane >> 4) << 3) + j;
    int o = (n << 4) + (lane & 15);
    wfrag[tid] = (__bf16)weight[b * 16384 + k * 128 + o];
}

// xb[type*N + row] = bf16(x_type[row]), 8 floats -> 8 bf16 per thread
__global__ __launch_bounds__(256) void cast_kernel(const float* __restrict__ x0,
                                                   const float* __restrict__ x1,
                                                   __bf16* __restrict__ xb) {
    int ty = blockIdx.y;
    const float* x = ty ? x1 : x0;
    __bf16* o = xb + (size_t)ty * HSZ;
    int i = blockIdx.x * 256 + threadIdx.x;
    float4 f0 = reinterpret_cast<const float4*>(x)[2 * i];
    float4 f1 = reinterpret_cast<const float4*>(x)[2 * i + 1];
    union { __bf16 b[8]; uint4 v; } pk;
    pk.b[0] = (__bf16)f0.x; pk.b[1] = (__bf16)f0.y;
    pk.b[2] = (__bf16)f0.z; pk.b[3] = (__bf16)f0.w;
    pk.b[4] = (__bf16)f1.x; pk.b[5] = (__bf16)f1.y;
    pk.b[6] = (__bf16)f1.z; pk.b[7] = (__bf16)f1.w;
    reinterpret_cast<uint4*>(o)[i] = pk.v;
}

// Combined-slot histogram: slot = dstntype*N + dst. i in [0, 4E).
__global__ __launch_bounds__(256) void hist4_kernel(const int* __restrict__ d0,
                                                    const int* __restrict__ d1,
                                                    const int* __restrict__ d2,
                                                    const int* __restrict__ d3,
                                                    int* __restrict__ counts) {
    int i = blockIdx.x * 256 + threadIdx.x;
    int rel = i / NEDGE;
    int e = i - rel * NEDGE;
    int slot = rel == 0 ? d0[e] : rel == 1 ? N_NODES + d1[e]
             : rel == 2 ? d2[e] : N_NODES + d3[e];
    atomicAdd(&counts[slot], 1);
}

// Per-block partial sums over the single CS2 array: 98 blocks x 1024 counts.
__global__ __launch_bounds__(256) void block_sums_kernel(const int* __restrict__ counts,
                                                         int* __restrict__ partials) {
    const int4* base = reinterpret_cast<const int4*>(counts) + blockIdx.x * 256;
    int4 v = base[threadIdx.x];
    int s = v.x + v.y + v.z + v.w;
#pragma unroll
    for (int d = 1; d < 64; d <<= 1) s += __shfl_xor(s, d, 64);
    __shared__ int wsum[4];
    int wave = threadIdx.x >> 6;
    int lane = threadIdx.x & 63;
    if (lane == 0) wsum[wave] = s;
    __syncthreads();
    if (threadIdx.x == 0)
        partials[blockIdx.x] = wsum[0] + wsum[1] + wsum[2] + wsum[3];
}

// Exclusive scan + write indptr and cursor (int4 stores). blk in [0,98).
__global__ __launch_bounds__(256) void scan_write_kernel(const int* __restrict__ counts,
                                                         const int* __restrict__ partials,
                                                         int* __restrict__ indptr,
                                                         int* __restrict__ cursor) {
    int blk = blockIdx.x;
    int lane = threadIdx.x & 63;
    int wave = threadIdx.x >> 6;

    int pv = (lane < blk ? partials[lane] : 0) +
             (lane + 64 < blk ? partials[lane + 64] : 0);
#pragma unroll
    for (int d = 1; d < 64; d <<= 1) pv += __shfl_xor(pv, d, 64);

    const int4* base = reinterpret_cast<const int4*>(counts) + blk * 256;
    int4 v = base[threadIdx.x];
    int ts = v.x + v.y + v.z + v.w;

    int s = ts;
#pragma unroll
    for (int d = 1; d < 64; d <<= 1) {
        int n = __shfl_up(s, d, 64);
        if (lane >= d) s += n;
    }
    int exclw = s - ts;

    __shared__ int wtot[4];
    if (lane == 63) wtot[wave] = s;
    __syncthreads();
    int woff = 0;
    if (wave > 0) woff += wtot[0];
    if (wave > 1) woff += wtot[1];
    if (wave > 2) woff += wtot[2];

    int e0 = pv + woff + exclw;
    int4 ip;
    ip.x = e0;
    ip.y = e0 + v.x;
    ip.z = ip.y + v.y;
    ip.w = ip.z + v.z;
    reinterpret_cast<int4*>(indptr)[blk * 256 + threadIdx.x] = ip;
    reinterpret_cast<int4*>(cursor)[blk * 256 + threadIdx.x] = ip;
}

// srcids[pos] = global src row (type1 sources offset by N), pos = cursor[slot]++
__global__ __launch_bounds__(256) void fill4_kernel(const int* __restrict__ s0, const int* __restrict__ d0,
                                                    const int* __restrict__ s1, const int* __restrict__ d1,
                                                    const int* __restrict__ s2, const int* __restrict__ d2,
                                                    const int* __restrict__ s3, const int* __restrict__ d3,
                                                    int* __restrict__ cursor,
                                                    int* __restrict__ srcids) {
    int i = blockIdx.x * 256 + threadIdx.x;
    int rel = i / NEDGE;
    int e = i - rel * NEDGE;
    int slot, gsrc;
    if (rel == 0)      { slot = d0[e];           gsrc = s0[e]; }
    else if (rel == 1) { slot = N_NODES + d1[e]; gsrc = s1[e]; }
    else if (rel == 2) { slot = d2[e];           gsrc = N_NODES + s2[e]; }
    else               { slot = N_NODES + d3[e]; gsrc = N_NODES + s3[e]; }
    int pos = atomicAdd(&cursor[slot], 1);
    srcids[pos] = gsrc;
}

// One wave per dst slot: y[slot][b][:] = sum_edges c_{rel,b} * xb[gsrc][:], b=0,1.
// rel = p + 2*(gsrc>=N); coefficients from w_comp. 4-way MLP unroll, f32 accum.
__global__ __launch_bounds__(256) void aggregate_y_kernel(const __bf16* __restrict__ xb,
                                                          const int* __restrict__ indptr,
                                                          const int* __restrict__ srcids,
                                                          const float* __restrict__ wcomp,
                                                          __bf16* __restrict__ y) {
    int idx = blockIdx.x * 256 + threadIdx.x;
    int slot = idx >> 6;
    int lane = idx & 63;
    int p = slot >= N_NODES;

    int beg = indptr[slot];
    int d = indptr[slot + 1] - beg;
    const int* sp = srcids + beg;

    float cA0 = wcomp[p * 2],       cA1 = wcomp[p * 2 + 1];
    float cB0 = wcomp[(p + 2) * 2], cB1 = wcomp[(p + 2) * 2 + 1];

    const unsigned int* xbu = reinterpret_cast<const unsigned int*>(xb);
    float y0l = 0.f, y0h = 0.f, y1l = 0.f, y1h = 0.f;

    for (int i = 0; i < d; i += 4) {
        unsigned int hv[4];
        float c0v[4], c1v[4];
#pragma unroll
        for (int k = 0; k < 4; ++k) {
            int j = i + k;
            int jc = j < d ? j : d - 1;        // clamp -> L1-hit re-read
            int s = sp[jc];
            bool isB = s >= N_NODES;
            c0v[k] = isB ? cB0 : cA0;
            c1v[k] = isB ? cB1 : cA1;
            unsigned int v = xbu[(unsigned)s * 64u + (unsigned)lane];
            hv[k] = j < d ? v : 0u;
        }
#pragma unroll
        for (int k = 0; k < 4; ++k) {
            union { unsigned int u; float f; } lo, hi;
            lo.u = hv[k] << 16;
            hi.u = hv[k] & 0xFFFF0000u;
            y0l += c0v[k] * lo.f;
            y0h += c0v[k] * hi.f;
            y1l += c1v[k] * lo.f;
            y1h += c1v[k] * hi.f;
        }
    }

    union { __bf16 b[2]; unsigned int u; } p0, p1;
    p0.b[0] = (__bf16)y0l; p0.b[1] = (__bf16)y0h;
    p1.b[0] = (__bf16)y1l; p1.b[1] = (__bf16)y1h;
    unsigned int* yu = reinterpret_cast<unsigned int*>(y);
    yu[(size_t)slot * 128 + lane] = p0.u;        // basis 0 features
    yu[(size_t)slot * 128 + 64 + lane] = p1.u;   // basis 1 features
}

// out[slot] = y[slot][0]*B0 + y[slot][1]*B1 + bias. Operand-swapped MFMA
// (basis W^T as A) -> float4 stores. 64 slots/block, basis frags in LDS.
__global__ __launch_bounds__(256) void gemm_out_kernel(const __bf16* __restrict__ y,
                                                       const __bf16* __restrict__ wfrag,
                                                       const float* __restrict__ bias,
                                                       float* __restrict__ out) {
    __shared__ __bf16 wl[32768];  // 64 KB: both basis frag sets
    {
        const uint4* s = reinterpret_cast<const uint4*>(wfrag);
        uint4* dst = reinterpret_cast<uint4*>(wl);
        int t = threadIdx.x;
#pragma unroll
        for (int i = 0; i < 16; ++i) dst[t + i * 256] = s[t + i * 256];
    }
    __syncthreads();

    const int lane = threadIdx.x & 63;
    const int wave = threadIdx.x >> 6;
    const int g = lane >> 4;
    const int m15 = lane & 15;

    int node = blockIdx.x * 64 + wave * 16 + m15;
    int nodec = node < NSLOT ? node : NSLOT - 1;
    const __bf16* yr = y + (size_t)nodec * 256 + g * 8;

    bf16x8 yfrag[2][4];
#pragma unroll
    for (int b = 0; b < 2; ++b)
#pragma unroll
        for (int kk = 0; kk < 4; ++kk)
            yfrag[b][kk] = *reinterpret_cast<const bf16x8*>(yr + b * 128 + kk * 32);

    const bf16x8* wv = reinterpret_cast<const bf16x8*>(wl);
    bool valid = node < NSLOT;
    float* orow = out + (size_t)node * 128;

#pragma unroll
    for (int n = 0; n < 8; ++n) {
        float4 bv = *reinterpret_cast<const float4*>(bias + n * 16 + g * 4);
        f32x4 acc = (f32x4){bv.x, bv.y, bv.z, bv.w};
#pragma unroll
        for (int b = 0; b < 2; ++b)
#pragma unroll
            for (int kk = 0; kk < 4; ++kk)
                acc = __builtin_amdgcn_mfma_f32_16x16x32_bf16(
                    wv[((b * 8 + n) * 4 + kk) * 64 + lane], yfrag[b][kk], acc, 0, 0, 0);
        if (valid)
            *reinterpret_cast<float4*>(orow + n * 16 + g * 4) =
                (float4){acc[0], acc[1], acc[2], acc[3]};
    }
}

extern "C" void kernel_launch(void* const* d_in, const int* in_sizes, int n_in,
                              void* d_out, int out_size, void* d_ws, size_t ws_size,
                              hipStream_t stream) {
    const float* x0     = (const float*)d_in[0];
    const float* x1     = (const float*)d_in[1];
    const float* weight = (const float*)d_in[2];
    const float* wcomp  = (const float*)d_in[3];
    const float* bias   = (const float*)d_in[4];
    const int* src[4] = {(const int*)d_in[5], (const int*)d_in[7],
                         (const int*)d_in[9], (const int*)d_in[11]};
    const int* dst[4] = {(const int*)d_in[6], (const int*)d_in[8],
                         (const int*)d_in[10], (const int*)d_in[12]};
    float* out = (float*)d_out;

    char* ws = (char*)d_ws;
    __bf16* wfrag = (__bf16*)(ws + OFF_WFRAG);
    __bf16* xb    = (__bf16*)(ws + OFF_XB);
    __bf16* y     = (__bf16*)(ws + OFF_Y);
    int* counts   = (int*)(ws + OFF_CNT);
    int* indptr   = (int*)(ws + OFF_IPTR);
    int* cursor   = (int*)(ws + OFF_CUR);
    int* partials = (int*)(ws + OFF_PART);
    int* srcids   = (int*)(ws + OFF_SRC);

    wfrag_kernel<<<128, 256, 0, stream>>>(weight, wfrag);
    cast_kernel<<<dim3(3125, 2), 256, 0, stream>>>(x0, x1, xb);

    // ---- combined-slot CSR build ----
    hipMemsetAsync(counts, 0, (size_t)CS2 * 4, stream);
    hist4_kernel<<<4 * NEDGE / 256, 256, 0, stream>>>(
        dst[0], dst[1], dst[2], dst[3], counts);
    block_sums_kernel<<<BLKS, 256, 0, stream>>>(counts, partials);
    scan_write_kernel<<<BLKS, 256, 0, stream>>>(counts, partials, indptr, cursor);
    fill4_kernel<<<4 * NEDGE / 256, 256, 0, stream>>>(
        src[0], dst[0], src[1], dst[1], src[2], dst[2], src[3], dst[3],
        cursor, srcids);

    // ---- basis-weighted gather-sum into y ----
    aggregate_y_kernel<<<NSLOT * 64 / 256, 256, 0, stream>>>(
        xb, indptr, srcids, wcomp, y);

    // ---- dense epilogue: out = y0*B0 + y1*B1 + bias ----
    gemm_out_kernel<<<(NSLOT + 63) / 64, 256, 0, stream>>>(y, wfrag, bias, out);
}